// Round 3
// baseline (1934.723 us; speedup 1.0000x reference)
//
#include <hip/hip_runtime.h>
#include <math.h>

// ---------------------------------------------------------------------------
// Net_LV Monte-Carlo local-vol simulation, MI355X (gfx950)
// 256 blocks x 1024 threads (16 waves/CU = 4/SIMD). Each WAVE independently
// owns 8 paths end-to-end (wave-synchronous: no block barriers inside the
// step loop; per-wave s_waitcnt lgkmcnt(0) fences + in-order LDS pipe).
// Inner products use packed v_pk_fma_f32 via ext_vector float2.
// ---------------------------------------------------------------------------

#define TPB 1024
#define NBLK 256
#define MC 32768
#define NSTEPS 90
#define NGRID 91
#define RATEf 0.025f

typedef float v2f __attribute__((ext_vector_type(2)));
typedef float v4f __attribute__((ext_vector_type(4)));

// ---- d_out offsets (float elements), in reference return order ----
#define PATH_OFF   0
#define VARP_OFF   (MC*NGRID)
#define DL_OFF     (2*MC*NGRID)
#define PV_OFF     (2*MC*NGRID + MC)
#define VV_OFF     (PV_OFF + 63)
#define EP_OFF     (VV_OFF + 63)
#define MEAN_OFF   (EP_OFF + MC)
#define VAR_OFF    (MEAN_OFF + 1)
#define ERR_OFF    (VAR_OFF + 1)

// ---- workspace layout (doubles): per-block partial sums ----
#define WS_STRIDE  132
#define MEANE_SLOT (NBLK*WS_STRIDE)

// ---- LDS offsets (dwords) ----
enum : int {
  OFF_DW0 = 0,        // diff Wi row0 (t) [50]
  OFF_DW1 = 50,
  OFF_DBI = 100,
  OFF_DWO = 150,
  OFF_DBO = 200,
  OFF_DWH = 204,      // 3 * [50][50]
  OFF_DBH = 7704,     // 3 * [50]
  OFF_VW0 = 7854,     // cvv [30]
  OFF_VW1 = 7884,
  OFF_VBI = 7914,
  OFF_VWH = 7944,     // 2 * [30][30]
  OFF_VBH = 9744,     // 2 * [30]
  OFF_VWO = 9804,     // [30][64] (col 63 pad)
  OFF_VBO = 11724,    // [64]
  OFF_EBI = 11788,    // [20]
  OFF_EWH = 11808,    // 2 * [20][20]
  OFF_EBH = 12608,    // 2 * [20]
  OFF_EWO = 12648,    // [20]
  OFF_EBO = 12668,
  OFF_EWI = 12670,    // [3][92][20] = 5520
  OFF_H   = 18192,    // per-wave H: 16 * [52][8]
  OFF_SG  = 24848,    // per-wave S[8] + g[8]
  OFF_ESUM= 25104,    // 16 waves * 4 doubles
  SMEM_DW = 25232
};
#define SMEM_BYTES (SMEM_DW*4)

#define WFENCE()  asm volatile("s_waitcnt lgkmcnt(0)" ::: "memory")
#define CFENCE()  asm volatile("" ::: "memory")

__device__ __forceinline__ float softplus_f(float x) {
  return fmaxf(x, 0.0f) + log1pf(expf(-fabsf(x)));
}

// In-place hidden layer, 2-neuron tile (rows j0=2*ng, +1), 4 paths per lane.
// Reads rows 0..K-1, writes rows j0..j0+1. Wave-synchronous (lockstep reads
// precede writes; in-order LDS pipe; fences guard compiler ordering).
template<int K, int WS>
__device__ __forceinline__ void hidden_pk(float* sm, int Hb, int wb, int bb,
                                          int p4, int ng, bool act)
{
  const int j0 = 2*ng;
  v2f a0l = {0.f,0.f}, a0h = {0.f,0.f}, a1l = {0.f,0.f}, a1h = {0.f,0.f};
  if (act) {
#pragma unroll 5
    for (int k = 0; k < K; ++k) {
      const v4f x = *(const v4f*)&sm[Hb + k*8 + p4];
      const v2f w = *(const v2f*)&sm[wb + k*WS + j0];
      v2f xl; xl.x = x.x; xl.y = x.y;
      v2f xh; xh.x = x.z; xh.y = x.w;
      const v2f w0 = {w.x, w.x};
      const v2f w1 = {w.y, w.y};
      a0l = __builtin_elementwise_fma(w0, xl, a0l);
      a0h = __builtin_elementwise_fma(w0, xh, a0h);
      a1l = __builtin_elementwise_fma(w1, xl, a1l);
      a1h = __builtin_elementwise_fma(w1, xh, a1h);
    }
  }
  CFENCE();
  if (act) {
    const float b0 = sm[bb + j0];
    const float b1 = sm[bb + j0 + 1];
    const v4f z = {0.f,0.f,0.f,0.f};
    v4f v0; v0.x = a0l.x + b0; v0.y = a0l.y + b0; v0.z = a0h.x + b0; v0.w = a0h.y + b0;
    v4f v1; v1.x = a1l.x + b1; v1.y = a1l.y + b1; v1.z = a1h.x + b1; v1.w = a1h.y + b1;
    v0 = __builtin_elementwise_max(v0, z);
    v1 = __builtin_elementwise_max(v1, z);
    *(v4f*)&sm[Hb + (j0  )*8 + p4] = v0;
    *(v4f*)&sm[Hb + (j0+1)*8 + p4] = v1;
  }
  WFENCE();
}

// In-place hidden layer, 1-neuron tile (row j0=ng).
template<int K, int WS>
__device__ __forceinline__ void hidden_pk1(float* sm, int Hb, int wb, int bb,
                                           int p4, int ng, bool act)
{
  v2f al = {0.f,0.f}, ah = {0.f,0.f};
  if (act) {
#pragma unroll 5
    for (int k = 0; k < K; ++k) {
      const v4f x = *(const v4f*)&sm[Hb + k*8 + p4];
      const float w = sm[wb + k*WS + ng];
      v2f xl; xl.x = x.x; xl.y = x.y;
      v2f xh; xh.x = x.z; xh.y = x.w;
      const v2f ws = {w, w};
      al = __builtin_elementwise_fma(ws, xl, al);
      ah = __builtin_elementwise_fma(ws, xh, ah);
    }
  }
  CFENCE();
  if (act) {
    const float b = sm[bb + ng];
    const v4f z = {0.f,0.f,0.f,0.f};
    v4f v; v.x = al.x + b; v.y = al.y + b; v.z = ah.x + b; v.w = ah.y + b;
    v = __builtin_elementwise_max(v, z);
    *(v4f*)&sm[Hb + ng*8 + p4] = v;
  }
  WFENCE();
}

// Full diff net (2->50->50->50->50->1, softplus), per-wave (8 paths).
__device__ __forceinline__ float diff_full(float* sm, float tp, int Hb, int Sb,
                                           int p4, int ng, int pl, int oc)
{
  { // L1: rows 0..49 (2 rows per lane for ng<25)
    const v4f S4 = *(const v4f*)&sm[Sb + p4];
    if (ng < 25) {
#pragma unroll
      for (int jj = 0; jj < 2; ++jj) {
        const int j = 2*ng + jj;
        const float w0t = sm[OFF_DW0 + j] * tp;
        const float w1  = sm[OFF_DW1 + j];
        const float bi  = sm[OFF_DBI + j];
        v4f v;
        v.x = fmaxf(w0t + w1*S4.x + bi, 0.0f);
        v.y = fmaxf(w0t + w1*S4.y + bi, 0.0f);
        v.z = fmaxf(w0t + w1*S4.z + bi, 0.0f);
        v.w = fmaxf(w0t + w1*S4.w + bi, 0.0f);
        *(v4f*)&sm[Hb + j*8 + p4] = v;
      }
    }
  }
  WFENCE();
  hidden_pk<50,50>(sm, Hb, OFF_DWH + 0*2500, OFF_DBH + 0*50, p4, ng, ng < 25);
  hidden_pk<50,50>(sm, Hb, OFF_DWH + 1*2500, OFF_DBH + 1*50, p4, ng, ng < 25);
  hidden_pk<50,50>(sm, Hb, OFF_DWH + 2*2500, OFF_DBH + 2*50, p4, ng, ng < 25);
  // output 50->1: split-k over 8 octants, reduce via shfl
  float s = 0.0f;
#pragma unroll
  for (int kk = 0; kk < 7; ++kk) {
    const int k = oc*7 + kk;
    if (k < 50) s = fmaf(sm[Hb + k*8 + pl], sm[OFF_DWO + k], s);
  }
  s += __shfl_xor(s, 8); s += __shfl_xor(s, 16); s += __shfl_xor(s, 32);
  return softplus_f(s + sm[OFF_DBO]);
}

__device__ void load_weights(float* sm, int m, int tid,
  const float* dWi, const float* dbi_g, const float* dWh_g, const float* dbh_g,
  const float* dWo_g, const float* dbo_g,
  const float* vWi, const float* vbi_g, const float* vWh_g, const float* vbh_g,
  const float* vWo_g, const float* vbo_g,
  const float* ebi_g, const float* eWh_g, const float* ebh_g,
  const float* eWo_g, const float* ebo_g)
{
  for (int j = tid; j < 50; j += TPB) {
    sm[OFF_DW0+j] = dWi[m*100 + j];
    sm[OFF_DW1+j] = dWi[m*100 + 50 + j];
    sm[OFF_DBI+j] = dbi_g[m*50 + j];
    sm[OFF_DWO+j] = dWo_g[m*50 + j];
  }
  for (int idx = tid; idx < 7500; idx += TPB)
    sm[OFF_DWH+idx] = dWh_g[m*7500 + idx];
  for (int idx = tid; idx < 150; idx += TPB)
    sm[OFF_DBH+idx] = dbh_g[m*150 + idx];
  for (int j = tid; j < 30; j += TPB) {
    sm[OFF_VW0+j] = vWi[m*60 + j];
    sm[OFF_VW1+j] = vWi[m*60 + 30 + j];
    sm[OFF_VBI+j] = vbi_g[m*30 + j];
  }
  for (int idx = tid; idx < 1800; idx += TPB)
    sm[OFF_VWH+idx] = vWh_g[m*1800 + idx];
  for (int idx = tid; idx < 60; idx += TPB)
    sm[OFF_VBH+idx] = vbh_g[m*60 + idx];
  for (int idx = tid; idx < 1920; idx += TPB) {
    const int k = idx/64, j = idx%64;
    sm[OFF_VWO+idx] = (j<63) ? vWo_g[(m*30 + k)*63 + j] : 0.0f;
  }
  for (int j = tid; j < 64; j += TPB)
    sm[OFF_VBO+j] = (j<63) ? vbo_g[m*63 + j] : 0.0f;
  for (int j = tid; j < 20; j += TPB) {
    sm[OFF_EBI+j] = ebi_g[m*20 + j];
    sm[OFF_EWO+j] = eWo_g[m*20 + j];
  }
  for (int idx = tid; idx < 800; idx += TPB)
    sm[OFF_EWH+idx] = eWh_g[m*800 + idx];
  for (int idx = tid; idx < 40; idx += TPB)
    sm[OFF_EBH+idx] = ebh_g[m*40 + idx];
  if (tid == 0) { sm[OFF_DBO] = dbo_g[m]; sm[OFF_EBO] = ebo_g[m]; }
}

extern "C" __global__ void __launch_bounds__(TPB, 4)
sim_kernel(const float* __restrict__ S0g, const float* __restrict__ zg,
           const float* dWi, const float* dbi_g, const float* dWh_g,
           const float* dbh_g, const float* dWo_g, const float* dbo_g,
           const float* vWi, const float* vbi_g, const float* vWh_g,
           const float* vbh_g, const float* vWo_g, const float* vbo_g,
           const float* eWi, const float* ebi_g, const float* eWh_g,
           const float* ebh_g, const float* eWo_g, const float* ebo_g,
           float* __restrict__ out, double* __restrict__ wsd)
{
  extern __shared__ float sm[];
  const int tid  = threadIdx.x;
  const int wv   = tid >> 6;          // wave 0..15
  const int lane = tid & 63;
  const int pg   = lane & 1;          // path-quad group (paths 0-3 / 4-7)
  const int ng   = lane >> 1;         // 0..31 neuron-tile index
  const int p4   = pg * 4;
  const int pl   = lane & 7;          // path 0..7
  const int oc   = lane >> 3;         // octant 0..7
  const int Hb = OFF_H  + wv * 416;   // [52][8]
  const int Sb = OFF_SG + wv * 16;
  const int Gb = Sb + 8;
  const int P0 = blockIdx.x * 128 + wv * 8;
  const float S0v = S0g[0];

  // cve_Wi for all 3 period nets ([3][92][20]) — loaded once
  for (int idx = tid; idx < 5520; idx += TPB) sm[OFF_EWI + idx] = eWi[idx];

  // per-lane persistent state
  v2f cv0l = {0.f,0.f}, cv0h = {0.f,0.f}, cv1l = {0.f,0.f}, cv1h = {0.f,0.f};
  float S = S0v, rmax = S0v, cve = 0.0f;

  if (lane < 8) {
    sm[Sb + pl] = S0v;
    out[PATH_OFF + (size_t)(P0 + pl) * NGRID + 0] = S0v;
  }
  __syncthreads();   // EWI + Sb ready

  // incremental cve-L1 accumulators: rows 3*oc+jj (<20), path pl
  float accCur[3], accN[3], accN2[3];
#pragma unroll
  for (int jj = 0; jj < 3; ++jj) {
    const int j = 3*oc + jj;
    const int r1 = 20 + j;           // EWI row 1 (path[0] term)
    const bool a = (j < 20);
    accCur[jj] = a ? S0v * sm[OFF_EWI + 0*1840 + r1] : 0.0f;
    accN[jj]   = a ? S0v * sm[OFF_EWI + 1*1840 + r1] : 0.0f;
    accN2[jj]  = a ? S0v * sm[OFF_EWI + 2*1840 + r1] : 0.0f;
  }

  for (int m = 0; m < 3; ++m) {
    if (m > 0) {
#pragma unroll
      for (int jj = 0; jj < 3; ++jj) { accCur[jj] = accN[jj]; accN[jj] = accN2[jj]; }
    }
    __syncthreads();   // prior period fully done (incl. psum reduce)
    load_weights(sm, m, tid, dWi, dbi_g, dWh_g, dbh_g, dWo_g, dbo_g,
                 vWi, vbi_g, vWh_g, vbh_g, vWo_g, vbo_g,
                 ebi_g, eWh_g, ebh_g, eWo_g, ebo_g);
    __syncthreads();

    if (m == 0) {   // d0 / var0
      const float d0 = diff_full(sm, 0.0f, Hb, Sb, p4, ng, pl, oc);
      if (lane < 8)
        out[VARP_OFF + (size_t)(P0 + pl) * NGRID + 0] = d0 * d0;
      WFENCE();
    }

    for (int it = 1; it <= 30; ++it) {
      const int i = m*30 + it;
      const float ti = 0.01f * (float)i;
      const float tp = 0.01f * (float)(i - 1);
      const float hstep = ti - tp;
      const float sqh = sqrtf(hstep);
      const float disc = expf(-RATEf * tp);
      const float zval = zg[(size_t)(P0 + pl) * NSTEPS + (i - 1)];
      const float dWv = sqh * zval;

      // ---------------- diff net ----------------
      const float d = diff_full(sm, tp, Hb, Sb, p4, ng, pl, oc);
      const float g = ((disc * S) * d) * dWv;   // S is old S

      CFENCE();   // diff-out reads precede the writes below
      // ---- vL1 (rows 0..29) + g/varp/DL writes ----
      {
        const v4f S4 = *(const v4f*)&sm[Sb + p4];
        if (ng < 15) {
#pragma unroll
          for (int jj = 0; jj < 2; ++jj) {
            const int j = 2*ng + jj;
            const float w0t = sm[OFF_VW0 + j] * tp;
            const float w1  = sm[OFF_VW1 + j];
            const float bi  = sm[OFF_VBI + j];
            v4f v;
            v.x = fmaxf(w0t + w1*S4.x + bi, 0.0f);
            v.y = fmaxf(w0t + w1*S4.y + bi, 0.0f);
            v.z = fmaxf(w0t + w1*S4.z + bi, 0.0f);
            v.w = fmaxf(w0t + w1*S4.w + bi, 0.0f);
            *(v4f*)&sm[Hb + j*8 + p4] = v;
          }
        }
      }
      if (lane < 8) {
        sm[Gb + pl] = g;
        out[VARP_OFF + (size_t)(P0 + pl) * NGRID + i] = d * d;
        if (i == NSTEPS) out[DL_OFF + (P0 + pl)] = d;
      }
      WFENCE();

      hidden_pk1<30,30>(sm, Hb, OFF_VWH + 0*900, OFF_VBH + 0*30, p4, ng, ng < 30);
      hidden_pk1<30,30>(sm, Hb, OFF_VWH + 1*900, OFF_VBH + 1*30, p4, ng, ng < 30);

      // ---- vOut (reads H rows 0..29, Gb) + eL1 (writes rows 0..19) ----
      {
        v2f a0l = {0.f,0.f}, a0h = {0.f,0.f}, a1l = {0.f,0.f}, a1h = {0.f,0.f};
        const int j0 = 2*ng;
#pragma unroll 5
        for (int k = 0; k < 30; ++k) {
          const v4f x = *(const v4f*)&sm[Hb + k*8 + p4];
          const v2f w = *(const v2f*)&sm[OFF_VWO + k*64 + j0];
          v2f xl; xl.x = x.x; xl.y = x.y;
          v2f xh; xh.x = x.z; xh.y = x.w;
          const v2f w0 = {w.x, w.x};
          const v2f w1 = {w.y, w.y};
          a0l = __builtin_elementwise_fma(w0, xl, a0l);
          a0h = __builtin_elementwise_fma(w0, xh, a0h);
          a1l = __builtin_elementwise_fma(w1, xl, a1l);
          a1h = __builtin_elementwise_fma(w1, xh, a1h);
        }
        const v4f g4 = *(const v4f*)&sm[Gb + p4];
        CFENCE();   // vOut reads precede eL1 writes
        { // eL1: rows 3*oc+jj (<20), col pl
          const int ewb = OFF_EWI + m*1840;
#pragma unroll
          for (int jj = 0; jj < 3; ++jj) {
            const int j = 3*oc + jj;
            if (j < 20) {
              const float v = sm[ewb + j]*tp + accCur[jj] + sm[OFF_EBI + j];
              sm[Hb + j*8 + pl] = fmaxf(v, 0.0f);
            }
          }
        }
        WFENCE();
        // cvv accumulate (registers only)
        const float b0 = sm[OFF_VBO + j0];
        const float b1 = sm[OFF_VBO + j0 + 1];
        v2f gl; gl.x = g4.x; gl.y = g4.y;
        v2f gh; gh.x = g4.z; gh.y = g4.w;
        const v2f b0s = {b0, b0}, b1s = {b1, b1};
        cv0l = __builtin_elementwise_fma(gl, a0l + b0s, cv0l);
        cv0h = __builtin_elementwise_fma(gh, a0h + b0s, cv0h);
        cv1l = __builtin_elementwise_fma(gl, a1l + b1s, cv1l);
        cv1h = __builtin_elementwise_fma(gh, a1h + b1s, cv1h);
      }

      hidden_pk1<20,20>(sm, Hb, OFF_EWH + 0*400, OFF_EBH + 0*20, p4, ng, ng < 20);
      hidden_pk1<20,20>(sm, Hb, OFF_EWH + 1*400, OFF_EBH + 1*20, p4, ng, ng < 20);

      // ---- eOut, cve, state update, acc updates ----
      float oute;
      {
        float s_ = 0.0f;
#pragma unroll
        for (int kk = 0; kk < 3; ++kk) {
          const int k = oc*3 + kk;
          if (k < 20) s_ = fmaf(sm[Hb + k*8 + pl], sm[OFF_EWO + k], s_);
        }
        s_ += __shfl_xor(s_, 8); s_ += __shfl_xor(s_, 16); s_ += __shfl_xor(s_, 32);
        oute = s_ + sm[OFF_EBO];
      }
      cve = fmaf(g, oute, cve);

      const float Sold = S;
      const float t1 = (RATEf*Sold*hstep) / (1.0f + (RATEf*Sold)*sqh);
      const float t2 = ((Sold*d)*dWv)     / (1.0f + (Sold*d)*sqh);
      const float Snew = (Sold + t1) + t2;
      S = Snew;
      rmax = fmaxf(rmax, Snew);
      if (lane < 8) {
        out[PATH_OFF + (size_t)(P0 + pl) * NGRID + i] = Snew;
        sm[Sb + pl] = Snew;   // last Sb read (vL1) already issued; in-order pipe
      }
      { // incremental cve-L1 update with EWI row (1+i)
        const int roff = (1 + i)*20;
        const int bm = m*1840;
        const int bn = (m < 2 ? m + 1 : 2) * 1840;
#pragma unroll
        for (int jj = 0; jj < 3; ++jj) {
          const int j = 3*oc + jj;
          if (j < 20) {
            accCur[jj] = fmaf(Snew, sm[OFF_EWI + bm   + roff + j], accCur[jj]);
            accN[jj]   = fmaf(Snew, sm[OFF_EWI + bn   + roff + j], accN[jj]);
            accN2[jj]  = fmaf(Snew, sm[OFF_EWI + 3680 + roff + j], accN2[jj]);
          }
        }
      }
      WFENCE();   // Sb write visible before next iteration's L1 read
    } // steps

    // ---------------- period-end price partials (per wave, H as scratch) ----
    {
      const float discm = expf(-RATEf * (0.01f * (float)(30*(m+1))));
      double* ps = (double*)&sm[Hb];
#pragma unroll
      for (int cc = 0; cc < 2; ++cc) {
        const int col = 2*ng + cc;
        const bool actp = (col >= 21*m) && (col < 21*m + 21);
        double s1 = 0.0, s2 = 0.0;
        if (actp) {
          const float Kst = 0.8f + 0.02f * (float)(col - 21*m);
          const v2f cl = (cc == 0) ? cv0l : cv1l;
          const v2f ch = (cc == 0) ? cv0h : cv1h;
#pragma unroll
          for (int l = 0; l < 4; ++l) {
            const float Sp = sm[Sb + p4 + l];
            const float cvval = (l == 0) ? cl.x : (l == 1) ? cl.y
                              : (l == 2) ? ch.x : ch.y;
            const float pr_ = discm * fmaxf(Sp - Kst, 0.0f) - cvval;
            s1 += (double)pr_;
            s2 += (double)pr_ * (double)pr_;
          }
        }
        s1 += __shfl_xor(s1, 1);
        s2 += __shfl_xor(s2, 1);
        if (actp && pg == 0) {
          const int sI = col - 21*m;
          ps[sI*2 + 0] = s1;
          ps[sI*2 + 1] = s2;
        }
      }
    }
    __syncthreads();
    if (tid < 21) {
      double a = 0.0, b = 0.0;
      for (int w = 0; w < 16; ++w) {
        const double* pw = (const double*)&sm[OFF_H + w*416];
        a += pw[tid*2 + 0];
        b += pw[tid*2 + 1];
      }
      wsd[(size_t)blockIdx.x*WS_STRIDE + (m*21+tid)*2 + 0] = a;
      wsd[(size_t)blockIdx.x*WS_STRIDE + (m*21+tid)*2 + 1] = b;
    }
  } // periods

  // ---------------- exotic outputs & partials ----------------
  const float discT = expf(-RATEf * (0.01f * 90.0f));
  const float e  = discT * (rmax - S);
  const float ep = e - cve;
  if (lane < 8) out[EP_OFF + (P0 + pl)] = ep;
  double de  = (lane < 8) ? (double)e  : 0.0;
  double dp  = (lane < 8) ? (double)ep : 0.0;
  double dp2 = (lane < 8) ? (double)ep * (double)ep : 0.0;
#pragma unroll
  for (int msk = 1; msk <= 32; msk <<= 1) {
    de  += __shfl_xor(de,  msk);
    dp  += __shfl_xor(dp,  msk);
    dp2 += __shfl_xor(dp2, msk);
  }
  {
    double* es = (double*)&sm[OFF_ESUM];
    if (lane == 0) { es[wv*4+0] = de; es[wv*4+1] = dp; es[wv*4+2] = dp2; }
  }
  __syncthreads();
  if (tid == 0) {
    double* es = (double*)&sm[OFF_ESUM];
    double a = 0, b = 0, c = 0;
    for (int w = 0; w < 16; ++w) { a += es[w*4]; b += es[w*4+1]; c += es[w*4+2]; }
    wsd[(size_t)blockIdx.x*WS_STRIDE + 126] = a;
    wsd[(size_t)blockIdx.x*WS_STRIDE + 127] = b;
    wsd[(size_t)blockIdx.x*WS_STRIDE + 128] = c;
  }
}

extern "C" __global__ void finalize_kernel(double* __restrict__ wsd,
                                           float* __restrict__ out)
{
  const int t = threadIdx.x;
  if (t < 63) {
    double a = 0.0, b = 0.0;
    for (int blk = 0; blk < NBLK; ++blk) {
      a += wsd[(size_t)blk*WS_STRIDE + t*2 + 0];
      b += wsd[(size_t)blk*WS_STRIDE + t*2 + 1];
    }
    const double mean = a / (double)MC;
    const double var  = (b - a*a/(double)MC) / (double)(MC - 1);
    out[PV_OFF + t] = (float)mean;
    out[VV_OFF + t] = (float)var;
  } else if (t == 64) {
    double a = 0.0;
    for (int blk = 0; blk < NBLK; ++blk) a += wsd[(size_t)blk*WS_STRIDE + 126];
    wsd[MEANE_SLOT] = a / (double)MC;
  } else if (t == 65) {
    double a = 0.0, c = 0.0;
    for (int blk = 0; blk < NBLK; ++blk) {
      a += wsd[(size_t)blk*WS_STRIDE + 127];
      c += wsd[(size_t)blk*WS_STRIDE + 128];
    }
    out[MEAN_OFF] = (float)(a / (double)MC);
    out[VAR_OFF]  = (float)((c - a*a/(double)MC) / (double)(MC - 1));
  }
}

extern "C" __global__ void error_kernel(const double* __restrict__ wsd,
                                        float* __restrict__ out)
{
  const int p = blockIdx.x * 256 + threadIdx.x;
  if (p < MC) {
    const float meanE = (float)wsd[MEANE_SLOT];
    out[ERR_OFF + p] = out[EP_OFF + p] - meanE;
  }
}

extern "C" void kernel_launch(void* const* d_in, const int* in_sizes, int n_in,
                              void* d_out, int out_size, void* d_ws, size_t ws_size,
                              hipStream_t stream)
{
  (void)in_sizes; (void)n_in; (void)out_size; (void)ws_size;
  const float* S0g  = (const float*)d_in[0];
  const float* zg   = (const float*)d_in[1];
  // d_in[2..4] = MC_samples / ind_T / period_length (fixed constants)
  const float* dWi  = (const float*)d_in[5];
  const float* dbi  = (const float*)d_in[6];
  const float* dWh  = (const float*)d_in[7];
  const float* dbh  = (const float*)d_in[8];
  const float* dWo  = (const float*)d_in[9];
  const float* dbo  = (const float*)d_in[10];
  const float* vWi  = (const float*)d_in[11];
  const float* vbi  = (const float*)d_in[12];
  const float* vWh  = (const float*)d_in[13];
  const float* vbh  = (const float*)d_in[14];
  const float* vWo  = (const float*)d_in[15];
  const float* vbo  = (const float*)d_in[16];
  const float* eWi  = (const float*)d_in[17];
  const float* ebi  = (const float*)d_in[18];
  const float* eWh  = (const float*)d_in[19];
  const float* ebh  = (const float*)d_in[20];
  const float* eWo  = (const float*)d_in[21];
  const float* ebo  = (const float*)d_in[22];
  float* out  = (float*)d_out;
  double* wsd = (double*)d_ws;

  hipFuncSetAttribute(reinterpret_cast<const void*>(sim_kernel),
                      hipFuncAttributeMaxDynamicSharedMemorySize, SMEM_BYTES);

  sim_kernel<<<NBLK, TPB, SMEM_BYTES, stream>>>(
      S0g, zg, dWi, dbi, dWh, dbh, dWo, dbo,
      vWi, vbi, vWh, vbh, vWo, vbo,
      eWi, ebi, eWh, ebh, eWo, ebo, out, wsd);
  finalize_kernel<<<1, 128, 0, stream>>>(wsd, out);
  error_kernel<<<MC/256, 256, 0, stream>>>(wsd, out);
}

// Round 4
// 1692.848 us; speedup vs baseline: 1.1429x; 1.1429x over previous
//
#include <hip/hip_runtime.h>
#include <math.h>

// ---------------------------------------------------------------------------
// Net_LV Monte-Carlo local-vol simulation, MI355X (gfx950)
// 256 blocks x 512 threads; each WAVE-PAIR owns 32 paths end-to-end and
// splits the neuron dimension across the two waves. Ping-pong H buffers ->
// 1 barrier per layer. Inner tiles use packed f32 (v_pk_fma_f32) via v4f.
// ---------------------------------------------------------------------------

#define TPB 512
#define NBLK 256
#define MC 32768
#define NSTEPS 90
#define NGRID 91
#define RATEf 0.025f

typedef float v4f __attribute__((ext_vector_type(4)));

__device__ __forceinline__ v4f splat4(float s) { return (v4f){s, s, s, s}; }
__device__ __forceinline__ v4f zero4() { return (v4f){0.f, 0.f, 0.f, 0.f}; }

// ---- d_out offsets (float elements), in reference return order ----
#define PATH_OFF   0
#define VARP_OFF   (MC*NGRID)
#define DL_OFF     (2*MC*NGRID)
#define PV_OFF     (2*MC*NGRID + MC)
#define VV_OFF     (PV_OFF + 63)
#define EP_OFF     (VV_OFF + 63)
#define MEAN_OFF   (EP_OFF + MC)
#define VAR_OFF    (MEAN_OFF + 1)
#define ERR_OFF    (VAR_OFF + 1)

// ---- workspace layout (doubles): per-block partial sums ----
#define WS_STRIDE  132
#define MEANE_SLOT (NBLK*WS_STRIDE)

// ---- LDS offsets (dwords) ----
enum : int {
  OFF_DW0 = 0,        // diff Wi row0 (t), padded 52
  OFF_DW1 = 52,       // diff Wi row1 (S)
  OFF_DBI = 104,
  OFF_DWH = 156,      // 3 * [50][52]
  OFF_DBH = 7956,     // 3 * [52]
  OFF_DWO = 8112,     // [52]
  OFF_DBO = 8164,
  OFF_VW0 = 8168,     // cvv, padded 32 / [30][32] / [30][64]
  OFF_VW1 = 8200,
  OFF_VBI = 8232,
  OFF_VWH = 8264,     // 2 * [30][32]
  OFF_VBH = 10184,    // 2 * [32]
  OFF_VWO = 10248,    // [30][64]
  OFF_VBO = 12168,    // [64]
  OFF_EBI = 12232,    // cve
  OFF_EWH = 12264,    // 2 * [20][20]
  OFF_EBH = 13064,    // 2 * [32]
  OFF_EWO = 13128,    // [20]
  OFF_EBO = 13148,
  OFF_EWI = 13152,    // cve_Wi, all 3 nets: [3][92][20] = 5520
  OFF_H   = 18672,    // per-pair DOUBLE activation buffer: 4 * 2 * [52][36]
  OFF_S   = 33648,    // per-pair S[32]
  OFF_G   = 33776,    // per-pair g[32]
  OFF_PSUM = 33904,   // 168 doubles (price partials per pair)
  OFF_ESUM = 34240,   // 16 doubles
  SMEM_DW  = 34272
};
#define SMEM_BYTES (SMEM_DW*4)

__device__ __forceinline__ float softplus_f(float x) {
  return fmaxf(x, 0.0f) + log1pf(expf(-fabsf(x)));
}

// One hidden layer, ping-pong: reads Rb (rows 0..K-1), writes Wb (rows
// j0..j0+NJ-1), relu. Single barrier. Tile: 4 paths x NJ neurons, packed f32.
template<int K, int WS, int NJ>
__device__ __forceinline__ void hidden_layer2(float* sm, int Rb, int Wb,
                                              int wb, int bb, int p4, int j0,
                                              bool act)
{
  v4f acc[NJ];
#pragma unroll
  for (int n = 0; n < NJ; ++n) acc[n] = zero4();
  if (act) {
#pragma unroll 5
    for (int k = 0; k < K; ++k) {
      const v4f x = *(const v4f*)&sm[Rb + k*36 + p4];
      if constexpr (NJ == 4) {
        const v4f w = *(const v4f*)&sm[wb + k*WS + j0];
        acc[0] = __builtin_elementwise_fma(splat4(w.x), x, acc[0]);
        acc[1] = __builtin_elementwise_fma(splat4(w.y), x, acc[1]);
        acc[2] = __builtin_elementwise_fma(splat4(w.z), x, acc[2]);
        acc[3] = __builtin_elementwise_fma(splat4(w.w), x, acc[3]);
      } else {
        const float2 w = *(const float2*)&sm[wb + k*WS + j0];
        acc[0] = __builtin_elementwise_fma(splat4(w.x), x, acc[0]);
        acc[1] = __builtin_elementwise_fma(splat4(w.y), x, acc[1]);
      }
    }
#pragma unroll
    for (int n = 0; n < NJ; ++n) {
      const v4f v = __builtin_elementwise_max(acc[n] + splat4(sm[bb + j0 + n]),
                                              zero4());
      *(v4f*)&sm[Wb + (j0+n)*36 + p4] = v;
    }
  }
  __syncthreads();
}

// Full diff net (2->50->50->50->50->1, softplus). Neuron-split across the
// wave pair (j0 = 4*ng8 + 32*pr). Last hidden layer lands in Hb1.
__device__ __forceinline__ float diff_net(float* sm, float tp, int Hb0, int Hb1,
                                          int Sb, int p4, int j0, bool act52,
                                          int plane, int half)
{
  if (act52) {   // L1 -> H0 rows j0..j0+3 (50,51 zero pads)
    const v4f S4 = *(const v4f*)&sm[Sb + p4];
#pragma unroll
    for (int jj = 0; jj < 4; ++jj) {
      const int j = j0 + jj;
      const float c = fmaf(sm[OFF_DW0 + j], tp, sm[OFF_DBI + j]);
      v4f v = __builtin_elementwise_fma(splat4(sm[OFF_DW1 + j]), S4, splat4(c));
      v = __builtin_elementwise_max(v, zero4());
      *(v4f*)&sm[Hb0 + j*36 + p4] = v;
    }
  }
  __syncthreads();
  hidden_layer2<50,52,4>(sm, Hb0, Hb1, OFF_DWH,        OFF_DBH,       p4, j0, act52);
  hidden_layer2<50,52,4>(sm, Hb1, Hb0, OFF_DWH + 2600, OFF_DBH + 52,  p4, j0, act52);
  hidden_layer2<50,52,4>(sm, Hb0, Hb1, OFF_DWH + 5200, OFF_DBH + 104, p4, j0, act52);
  // output layer 50->1, split-k over wave halves (both waves redundantly)
  float s = 0.0f;
  const int k0 = half * 25;
#pragma unroll
  for (int kk = 0; kk < 25; ++kk) {
    const int k = k0 + kk;
    s = fmaf(sm[Hb1 + k*36 + plane], sm[OFF_DWO + k], s);
  }
  s += __shfl_xor(s, 32);
  return softplus_f(s + sm[OFF_DBO]);
}

__device__ void load_weights(float* sm, int m, int tid,
  const float* dWi, const float* dbi_g, const float* dWh_g, const float* dbh_g,
  const float* dWo_g, const float* dbo_g,
  const float* vWi, const float* vbi_g, const float* vWh_g, const float* vbh_g,
  const float* vWo_g, const float* vbo_g,
  const float* ebi_g, const float* eWh_g, const float* ebh_g,
  const float* eWo_g, const float* ebo_g)
{
  for (int j = tid; j < 52; j += TPB) {
    sm[OFF_DW0+j] = (j<50) ? dWi[m*100 + j]      : 0.0f;
    sm[OFF_DW1+j] = (j<50) ? dWi[m*100 + 50 + j] : 0.0f;
    sm[OFF_DBI+j] = (j<50) ? dbi_g[m*50 + j]     : 0.0f;
    sm[OFF_DWO+j] = (j<50) ? dWo_g[m*50 + j]     : 0.0f;
  }
  for (int idx = tid; idx < 7800; idx += TPB) {
    const int l = idx / 2600, r = idx % 2600, k = r / 52, j = r % 52;
    sm[OFF_DWH+idx] = (j<50) ? dWh_g[((m*3+l)*50 + k)*50 + j] : 0.0f;
  }
  for (int idx = tid; idx < 156; idx += TPB) {
    const int l = idx/52, j = idx%52;
    sm[OFF_DBH+idx] = (j<50) ? dbh_g[(m*3+l)*50 + j] : 0.0f;
  }
  for (int j = tid; j < 32; j += TPB) {
    sm[OFF_VW0+j] = (j<30) ? vWi[m*60 + j]      : 0.0f;
    sm[OFF_VW1+j] = (j<30) ? vWi[m*60 + 30 + j] : 0.0f;
    sm[OFF_VBI+j] = (j<30) ? vbi_g[m*30 + j]    : 0.0f;
    sm[OFF_EBI+j] = (j<20) ? ebi_g[m*20 + j]    : 0.0f;
  }
  for (int idx = tid; idx < 1920; idx += TPB) {
    const int l = idx/960, r = idx%960, k = r/32, j = r%32;
    sm[OFF_VWH+idx] = (j<30) ? vWh_g[((m*2+l)*30 + k)*30 + j] : 0.0f;
  }
  for (int idx = tid; idx < 64; idx += TPB) {
    const int l = idx/32, j = idx%32;
    sm[OFF_VBH+idx] = (j<30) ? vbh_g[(m*2+l)*30 + j] : 0.0f;
    sm[OFF_EBH+idx] = (j<20) ? ebh_g[(m*2+l)*20 + j] : 0.0f;
  }
  for (int idx = tid; idx < 1920; idx += TPB) {
    const int k = idx/64, j = idx%64;
    sm[OFF_VWO+idx] = (j<63) ? vWo_g[(m*30 + k)*63 + j] : 0.0f;
  }
  for (int j = tid; j < 64; j += TPB)
    sm[OFF_VBO+j] = (j<63) ? vbo_g[m*63 + j] : 0.0f;
  for (int idx = tid; idx < 800; idx += TPB) {
    const int l = idx/400, r = idx%400, k = r/20, j = r%20;
    sm[OFF_EWH+idx] = eWh_g[((m*2+l)*20 + k)*20 + j];
  }
  for (int j = tid; j < 20; j += TPB)
    sm[OFF_EWO+j] = eWo_g[m*20 + j];
  if (tid == 0) { sm[OFF_DBO] = dbo_g[m]; sm[OFF_EBO] = ebo_g[m]; }
}

extern "C" __global__ void __launch_bounds__(TPB, 1)
sim_kernel(const float* __restrict__ S0g, const float* __restrict__ zg,
           const float* dWi, const float* dbi_g, const float* dWh_g,
           const float* dbh_g, const float* dWo_g, const float* dbo_g,
           const float* vWi, const float* vbi_g, const float* vWh_g,
           const float* vbh_g, const float* vWo_g, const float* vbo_g,
           const float* eWi, const float* ebi_g, const float* eWh_g,
           const float* ebh_g, const float* eWo_g, const float* ebo_g,
           float* __restrict__ out, double* __restrict__ wsd)
{
  extern __shared__ float sm[];
  const int tid   = threadIdx.x;
  const int wp    = tid >> 7;          // wave pair 0..3
  const int pr    = (tid >> 6) & 1;    // parity within pair
  const int lane  = tid & 63;
  const int pg    = lane & 7;
  const int ng8   = lane >> 3;
  const int p4    = pg * 4;
  const int plane = lane & 31;
  const int half  = lane >> 5;
  const int q     = half + 2*pr;       // quarter for cve j-split
  const int j0d   = 4*ng8 + 32*pr;     // diff/vOut neuron tile base
  const bool act52 = (j0d < 52);
  const int j0v2  = 4*ng8 + 2*pr;      // cvv/cve 2-neuron tile base
  const int Hb0 = OFF_H + wp * 3744;
  const int Hb1 = Hb0 + 1872;
  const int Sb  = OFF_S + wp * 32;
  const int Gb  = OFF_G + wp * 32;
  const int P0  = blockIdx.x * 128 + wp * 32;
  const float S0v = S0g[0];

  // cve_Wi for all 3 period nets, loaded once ([3][92][20])
  for (int idx = tid; idx < 5520; idx += TPB) sm[OFF_EWI + idx] = eWi[idx];

  v4f cvv[4];   // this wave's 4-col slice (cols j0d..j0d+3) x 4 paths
#pragma unroll
  for (int b = 0; b < 4; ++b) cvv[b] = zero4();
  float S = S0v, rmax = S0v, cve = 0.0f;

  if (pr == 0 && lane < 32) {
    sm[Sb + plane] = S0v;
    out[PATH_OFF + (size_t)(P0 + plane) * NGRID + 0] = S0v;
  }
  __syncthreads();   // ewi + S_lds ready

  // incremental cve-L1 accumulators: acc[jj] = sum_k path[k]*Wi[1+k][q*5+jj]
  float accCur[5], accN[5], accN2[5];
#pragma unroll
  for (int jj = 0; jj < 5; ++jj) {
    const int r1 = 20 + q*5 + jj;      // row 1 (path[0] term)
    accCur[jj] = S0v * sm[OFF_EWI + 0*1840 + r1];
    accN[jj]   = S0v * sm[OFF_EWI + 1*1840 + r1];
    accN2[jj]  = S0v * sm[OFF_EWI + 2*1840 + r1];
  }

  for (int m = 0; m < 3; ++m) {
    if (m > 0) {
#pragma unroll
      for (int jj = 0; jj < 5; ++jj) { accCur[jj] = accN[jj]; accN[jj] = accN2[jj]; }
    }
    __syncthreads();
    load_weights(sm, m, tid, dWi, dbi_g, dWh_g, dbh_g, dWo_g, dbo_g,
                 vWi, vbi_g, vWh_g, vbh_g, vWo_g, vbo_g,
                 ebi_g, eWh_g, ebh_g, eWo_g, ebo_g);
    __syncthreads();

    if (m == 0) {   // d0 / var0 (t=0, S=S0, period-0 net)
      const float d0 = diff_net(sm, 0.0f, Hb0, Hb1, Sb, p4, j0d, act52, plane, half);
      if (pr == 0 && lane < 32)
        out[VARP_OFF + (size_t)(P0 + plane) * NGRID + 0] = d0 * d0;
    }

    for (int it = 1; it <= 30; ++it) {
      const int i = m*30 + it;
      const float ti = 0.01f * (float)i;
      const float tp = 0.01f * (float)(i - 1);
      const float hstep = ti - tp;
      const float sqh = sqrtf(hstep);
      const float disc = expf(-RATEf * tp);
      const float zval = zg[(size_t)(P0 + plane) * NSTEPS + (i - 1)];
      const float dWv = sqh * zval;

      __syncthreads();  // step start: H0 free, S_lds stable
      // ---------------- diff net (4 internal barriers) ----------------
      const float d = diff_net(sm, tp, Hb0, Hb1, Sb, p4, j0d, act52, plane, half);
      const float g = ((disc * S) * d) * dWv;   // S is old S here

      // ---- phase C: vL1 -> H0 rows (j0v2, j0v2+1); g/varp/DL writes ----
      {
        const v4f S4 = *(const v4f*)&sm[Sb + p4];
#pragma unroll
        for (int jj = 0; jj < 2; ++jj) {
          const int j = j0v2 + jj;
          const float c = fmaf(sm[OFF_VW0 + j], tp, sm[OFF_VBI + j]);
          v4f v = __builtin_elementwise_fma(splat4(sm[OFF_VW1 + j]), S4, splat4(c));
          v = __builtin_elementwise_max(v, zero4());
          *(v4f*)&sm[Hb0 + j*36 + p4] = v;
        }
      }
      if (pr == 0 && lane < 32) {
        sm[Gb + plane] = g;
        out[VARP_OFF + (size_t)(P0 + plane) * NGRID + i] = d * d;
        if (i == NSTEPS) out[DL_OFF + (P0 + plane)] = d;
      }
      __syncthreads();

      hidden_layer2<30,32,2>(sm, Hb0, Hb1, OFF_VWH,       OFF_VBH,      p4, j0v2, true);
      hidden_layer2<30,32,2>(sm, Hb1, Hb0, OFF_VWH + 960, OFF_VBH + 32, p4, j0v2, true);

      // ---- phase E: vOut (reads H0, Gb) + eL1 (writes H1) + cvv accum ----
      {
        v4f vacc[4];
#pragma unroll
        for (int b = 0; b < 4; ++b) vacc[b] = zero4();
#pragma unroll 5
        for (int k = 0; k < 30; ++k) {
          const v4f x = *(const v4f*)&sm[Hb0 + k*36 + p4];
          const v4f w = *(const v4f*)&sm[OFF_VWO + k*64 + j0d];
          vacc[0] = __builtin_elementwise_fma(splat4(w.x), x, vacc[0]);
          vacc[1] = __builtin_elementwise_fma(splat4(w.y), x, vacc[1]);
          vacc[2] = __builtin_elementwise_fma(splat4(w.z), x, vacc[2]);
          vacc[3] = __builtin_elementwise_fma(splat4(w.w), x, vacc[3]);
        }
        const v4f g4 = *(const v4f*)&sm[Gb + p4];
        { // eL1: rows q*5..q*5+4, col plane (writes H1 — free since eWh2 done)
          const int ewb = OFF_EWI + m*1840;
#pragma unroll
          for (int jj = 0; jj < 5; ++jj) {
            const int j = q*5 + jj;
            const float v = fmaf(sm[ewb + j], tp, accCur[jj] + sm[OFF_EBI + j]);
            sm[Hb1 + j*36 + plane] = fmaxf(v, 0.0f);
          }
        }
#pragma unroll
        for (int jj = 0; jj < 4; ++jj) {
          cvv[jj] = __builtin_elementwise_fma(
              g4, vacc[jj] + splat4(sm[OFF_VBO + j0d + jj]), cvv[jj]);
        }
      }
      __syncthreads();

      hidden_layer2<20,20,2>(sm, Hb1, Hb0, OFF_EWH,       OFF_EBH,      p4, j0v2, j0v2 < 20);
      hidden_layer2<20,20,2>(sm, Hb0, Hb1, OFF_EWH + 400, OFF_EBH + 32, p4, j0v2, j0v2 < 20);

      // ---- phase G: eOut (reads H1), cve, state update, acc updates ----
      float oute;
      {
        float s_ = 0.0f;
        const int k0 = half * 10;
#pragma unroll
        for (int kk = 0; kk < 10; ++kk) {
          const int k = k0 + kk;
          s_ = fmaf(sm[Hb1 + k*36 + plane], sm[OFF_EWO + k], s_);
        }
        s_ += __shfl_xor(s_, 32);
        oute = s_ + sm[OFF_EBO];
      }
      cve = fmaf(g, oute, cve);

      const float Sold = S;
      const float t1 = (RATEf*Sold*hstep) / (1.0f + (RATEf*Sold)*sqh);
      const float t2 = ((Sold*d)*dWv)     / (1.0f + (Sold*d)*sqh);
      const float Snew = (Sold + t1) + t2;
      S = Snew;
      rmax = fmaxf(rmax, Snew);
      if (pr == 0 && lane < 32) {
        out[PATH_OFF + (size_t)(P0 + plane) * NGRID + i] = Snew;
        sm[Sb + plane] = Snew;   // safe: last S_lds read was >=2 barriers ago
      }
      { // incremental cve-L1 update with row (1+i)
        const int roff = (1 + i)*20 + q*5;
        const int bm = m*1840;
        const int bn = (m < 2 ? m + 1 : 2) * 1840;
#pragma unroll
        for (int jj = 0; jj < 5; ++jj) {
          accCur[jj] = fmaf(Snew, sm[OFF_EWI + bm   + roff + jj], accCur[jj]);
          accN[jj]   = fmaf(Snew, sm[OFF_EWI + bn   + roff + jj], accN[jj]);
          accN2[jj]  = fmaf(Snew, sm[OFF_EWI + 3680 + roff + jj], accN2[jj]);
        }
      }
    } // steps

    // ---------------- period-end price partials ----------------
    __syncthreads();
    {
      const float discm = expf(-RATEf * (0.01f * (float)(30*(m+1))));
      double* ps = (double*)&sm[OFF_PSUM];
#pragma unroll
      for (int cc = 0; cc < 4; ++cc) {
        const int col = j0d + cc;
        const bool act = (col >= 21*m) && (col < 21*m + 21);
        double s1 = 0.0, s2 = 0.0;
        if (act) {
          const float Kst = 0.8f + 0.02f * (float)(col - 21*m);
#pragma unroll
          for (int l = 0; l < 4; ++l) {
            const float Sp = sm[Sb + p4 + l];
            const float pr_ = discm * fmaxf(Sp - Kst, 0.0f) - cvv[cc][l];
            s1 += (double)pr_;
            s2 += (double)pr_ * (double)pr_;
          }
        }
        s1 += __shfl_xor(s1, 1); s1 += __shfl_xor(s1, 2); s1 += __shfl_xor(s1, 4);
        s2 += __shfl_xor(s2, 1); s2 += __shfl_xor(s2, 2); s2 += __shfl_xor(s2, 4);
        if (act && pg == 0) {
          const int sI = col - 21*m;
          ps[(wp*21 + sI)*2 + 0] = s1;
          ps[(wp*21 + sI)*2 + 1] = s2;
        }
      }
    }
    __syncthreads();
    if (tid < 21) {
      double* ps = (double*)&sm[OFF_PSUM];
      double a = 0.0, b = 0.0;
      for (int w = 0; w < 4; ++w) { a += ps[(w*21+tid)*2]; b += ps[(w*21+tid)*2+1]; }
      wsd[(size_t)blockIdx.x*WS_STRIDE + (m*21+tid)*2 + 0] = a;
      wsd[(size_t)blockIdx.x*WS_STRIDE + (m*21+tid)*2 + 1] = b;
    }
  } // periods

  // ---------------- exotic outputs & partials ----------------
  const float discT = expf(-RATEf * (0.01f * 90.0f));
  const float e  = discT * (rmax - S);
  const float ep = e - cve;
  if (pr == 0 && lane < 32) out[EP_OFF + (P0 + plane)] = ep;
  double de  = (lane < 32) ? (double)e  : 0.0;
  double dp  = (lane < 32) ? (double)ep : 0.0;
  double dp2 = (lane < 32) ? (double)ep * (double)ep : 0.0;
#pragma unroll
  for (int msk = 1; msk <= 32; msk <<= 1) {
    de  += __shfl_xor(de,  msk);
    dp  += __shfl_xor(dp,  msk);
    dp2 += __shfl_xor(dp2, msk);
  }
  {
    double* es = (double*)&sm[OFF_ESUM];
    if (pr == 0 && lane == 0) { es[wp*4+0] = de; es[wp*4+1] = dp; es[wp*4+2] = dp2; }
  }
  __syncthreads();
  if (tid == 0) {
    double* es = (double*)&sm[OFF_ESUM];
    double a = 0, b = 0, c = 0;
    for (int w = 0; w < 4; ++w) { a += es[w*4]; b += es[w*4+1]; c += es[w*4+2]; }
    wsd[(size_t)blockIdx.x*WS_STRIDE + 126] = a;
    wsd[(size_t)blockIdx.x*WS_STRIDE + 127] = b;
    wsd[(size_t)blockIdx.x*WS_STRIDE + 128] = c;
  }
}

extern "C" __global__ void finalize_kernel(double* __restrict__ wsd,
                                           float* __restrict__ out)
{
  const int t = threadIdx.x;
  if (t < 63) {
    double a = 0.0, b = 0.0;
    for (int blk = 0; blk < NBLK; ++blk) {
      a += wsd[(size_t)blk*WS_STRIDE + t*2 + 0];
      b += wsd[(size_t)blk*WS_STRIDE + t*2 + 1];
    }
    const double mean = a / (double)MC;
    const double var  = (b - a*a/(double)MC) / (double)(MC - 1);
    out[PV_OFF + t] = (float)mean;
    out[VV_OFF + t] = (float)var;
  } else if (t == 64) {
    double a = 0.0;
    for (int blk = 0; blk < NBLK; ++blk) a += wsd[(size_t)blk*WS_STRIDE + 126];
    wsd[MEANE_SLOT] = a / (double)MC;
  } else if (t == 65) {
    double a = 0.0, c = 0.0;
    for (int blk = 0; blk < NBLK; ++blk) {
      a += wsd[(size_t)blk*WS_STRIDE + 127];
      c += wsd[(size_t)blk*WS_STRIDE + 128];
    }
    out[MEAN_OFF] = (float)(a / (double)MC);
    out[VAR_OFF]  = (float)((c - a*a/(double)MC) / (double)(MC - 1));
  }
}

extern "C" __global__ void error_kernel(const double* __restrict__ wsd,
                                        float* __restrict__ out)
{
  const int p = blockIdx.x * 256 + threadIdx.x;
  if (p < MC) {
    const float meanE = (float)wsd[MEANE_SLOT];
    out[ERR_OFF + p] = out[EP_OFF + p] - meanE;
  }
}

extern "C" void kernel_launch(void* const* d_in, const int* in_sizes, int n_in,
                              void* d_out, int out_size, void* d_ws, size_t ws_size,
                              hipStream_t stream)
{
  (void)in_sizes; (void)n_in; (void)out_size; (void)ws_size;
  const float* S0g  = (const float*)d_in[0];
  const float* zg   = (const float*)d_in[1];
  // d_in[2..4] = MC_samples / ind_T / period_length (fixed constants)
  const float* dWi  = (const float*)d_in[5];
  const float* dbi  = (const float*)d_in[6];
  const float* dWh  = (const float*)d_in[7];
  const float* dbh  = (const float*)d_in[8];
  const float* dWo  = (const float*)d_in[9];
  const float* dbo  = (const float*)d_in[10];
  const float* vWi  = (const float*)d_in[11];
  const float* vbi  = (const float*)d_in[12];
  const float* vWh  = (const float*)d_in[13];
  const float* vbh  = (const float*)d_in[14];
  const float* vWo  = (const float*)d_in[15];
  const float* vbo  = (const float*)d_in[16];
  const float* eWi  = (const float*)d_in[17];
  const float* ebi  = (const float*)d_in[18];
  const float* eWh  = (const float*)d_in[19];
  const float* ebh  = (const float*)d_in[20];
  const float* eWo  = (const float*)d_in[21];
  const float* ebo  = (const float*)d_in[22];
  float* out  = (float*)d_out;
  double* wsd = (double*)d_ws;

  hipFuncSetAttribute(reinterpret_cast<const void*>(sim_kernel),
                      hipFuncAttributeMaxDynamicSharedMemorySize, SMEM_BYTES);

  sim_kernel<<<NBLK, TPB, SMEM_BYTES, stream>>>(
      S0g, zg, dWi, dbi, dWh, dbh, dWo, dbo,
      vWi, vbi, vWh, vbh, vWo, vbo,
      eWi, ebi, eWh, ebh, eWo, ebo, out, wsd);
  finalize_kernel<<<1, 128, 0, stream>>>(wsd, out);
  error_kernel<<<MC/256, 256, 0, stream>>>(wsd, out);
}